// Round 5
// baseline (263.328 us; speedup 1.0000x reference)
//
#include <hip/hip_runtime.h>
#include <hip/hip_fp16.h>

#define IN_DIM 29
#define XDIM 32
#define OUT_DIM 64
#define BN_EPS 1e-5f

#define BW      32       // dsts per bucket (LDS tile: 32*64*4 = 8 KB -> 8 WG/CU wave cap)
#define BW_LOG  5
#define NBLK    64       // count/partition blocks (runs ~8 edges = 32 B)
#define TBLK    2048     // transform blocks inside fused kernel
#define MAXBUCK 4096     // static LDS arrays; n_nodes <= 131072
#define SENT    0        // ordered-u16 sentinel: any real enc > 0

// ===========================================================================
// out[d][o] = max_{src in N(d)} y[src][o] + (beta - a*mean - a*(W[:,29:32].node_d))[o]
// y[n][o] = a[o] * (W[o,:] . [feat_n; node_n]),  a = gamma*rsqrt(var+eps)
// y stored as monotone ordered-u16 fp16 encoding; empty segment -> 0.
// ===========================================================================

// --- K1: fused per-node transform (blocks >= NBLK) + bucket histogram
//         (blocks < NBLK). Independent inputs -> runs concurrently. ---------
__global__ __launch_bounds__(256) void fused_tc_kernel(
    const float* __restrict__ features, const float* __restrict__ node,
    const float* __restrict__ weight, const float* __restrict__ gamma,
    const float* __restrict__ rvar, unsigned short* __restrict__ yq,
    const int* __restrict__ edges, int* __restrict__ gHist,
    int n_nodes, int npw, int n_edges, int nbuck, int chunk)
{
    if (blockIdx.x < NBLK) {
        // ---- count role ----
        __shared__ int h[MAXBUCK];
        for (int i = threadIdx.x; i < nbuck; i += 256) h[i] = 0;
        __syncthreads();
        const int e0 = blockIdx.x * chunk;
        const int e1 = min(e0 + chunk, n_edges);
        for (int e = e0 + threadIdx.x; e < e1; e += 256)
            atomicAdd(&h[edges[2*e] >> BW_LOG], 1);
        __syncthreads();
        for (int i = threadIdx.x; i < nbuck; i += 256)
            gHist[i * NBLK + blockIdx.x] = h[i];
    } else {
        // ---- transform role ----
        const int lane = threadIdx.x & 63;
        const int wave = (((int)blockIdx.x - NBLK) * 256 + (int)threadIdx.x) >> 6;
        int n0 = wave * npw;
        int n1 = n0 + npw; if (n1 > n_nodes) n1 = n_nodes;

        float w[XDIM];
        const float4* wp = (const float4*)(weight + lane * XDIM);
#pragma unroll
        for (int q = 0; q < 8; ++q) {
            float4 v = wp[q];
            w[4*q+0] = v.x; w[4*q+1] = v.y; w[4*q+2] = v.z; w[4*q+3] = v.w;
        }
        const float a = gamma[lane] * __frsqrt_rn(rvar[lane] + BN_EPS);

        for (int n = n0; n < n1; ++n) {
            const float* f = features + (size_t)n * IN_DIM;
            float acc = 0.0f;
#pragma unroll
            for (int i = 0; i < IN_DIM; ++i) acc = fmaf(f[i], w[i], acc);
            const float* nd = node + (size_t)n * 3;
#pragma unroll
            for (int j = 0; j < 3; ++j) acc = fmaf(nd[j], w[IN_DIM + j], acc);
            unsigned short hh = __half_as_ushort(__float2half(acc * a));
            unsigned short enc = (hh & 0x8000) ? (unsigned short)(~hh)
                                               : (unsigned short)(hh | 0x8000);
            yq[(size_t)n * OUT_DIM + lane] = enc;
        }
    }
}

// --- scan over nbuck*NBLK (bucket-major); excl prefix + per-1024-block aux -
__global__ __launch_bounds__(256) void scan_a_kernel(
    const int* __restrict__ counts, int n,
    int* __restrict__ excl, int* __restrict__ aux)
{
    const int t = threadIdx.x;
    const int base = blockIdx.x * 1024 + t * 4;
    int v[4];
#pragma unroll
    for (int k = 0; k < 4; ++k) v[k] = (base + k < n) ? counts[base + k] : 0;
    int tsum = v[0] + v[1] + v[2] + v[3];

    const int lane = t & 63, wv = t >> 6;
    int x = tsum;
#pragma unroll
    for (int off = 1; off < 64; off <<= 1) {
        int y = __shfl_up(x, off);
        if (lane >= off) x += y;
    }
    __shared__ int wsum[4];
    if (lane == 63) wsum[wv] = x;
    __syncthreads();
    int wexcl = 0;
    for (int i = 0; i < wv; ++i) wexcl += wsum[i];
    int run = wexcl + x - tsum;
#pragma unroll
    for (int k = 0; k < 4; ++k) {
        if (base + k < n) excl[base + k] = run;
        run += v[k];
    }
    if (t == 255) aux[blockIdx.x] = run;
}

// single-block parallel exclusive scan of aux
__global__ __launch_bounds__(256) void scan_b_kernel(int* __restrict__ aux, int nb) {
    const int t = threadIdx.x;
    const int lane = t & 63, wv = t >> 6;
    __shared__ int wsum[4];
    __shared__ int s_run;
    if (t == 0) s_run = 0;
    __syncthreads();
    for (int base = 0; base < nb; base += 256) {
        const int i = base + t;
        int v = (i < nb) ? aux[i] : 0;
        int x = v;
#pragma unroll
        for (int off = 1; off < 64; off <<= 1) {
            int y = __shfl_up(x, off);
            if (lane >= off) x += y;
        }
        if (lane == 63) wsum[wv] = x;
        __syncthreads();
        int wexcl = 0;
        for (int k = 0; k < wv; ++k) wexcl += wsum[k];
        const int run = s_run;
        if (i < nb) aux[i] = run + wexcl + x - v;
        __syncthreads();
        if (t == 255) s_run = run + wexcl + x;
        __syncthreads();
    }
}

// --- K3: multisplit partition -> per-bucket contiguous key runs ------------
//         (adds aux on the fly; no scan_c pass)
__global__ __launch_bounds__(256) void partition_kernel(
    const int* __restrict__ edges, const int* __restrict__ gOffs,
    const int* __restrict__ aux,
    int* __restrict__ keys, int n_edges, int nbuck, int chunk)
{
    __shared__ int cur[MAXBUCK];
    for (int i = threadIdx.x; i < nbuck; i += 256) {
        const int idx = i * NBLK + blockIdx.x;
        cur[i] = gOffs[idx] + aux[idx >> 10];
    }
    __syncthreads();
    const int e0 = blockIdx.x * chunk;
    const int e1 = min(e0 + chunk, n_edges);
    for (int e = e0 + threadIdx.x; e < e1; e += 256) {
        const int dst = edges[2*e], src = edges[2*e+1];
        const int b = dst >> BW_LOG;
        const int pos = atomicAdd(&cur[b], 1);
        keys[pos] = (dst & (BW - 1)) | (src << BW_LOG);
    }
}

// --- K4: fused pool. One WG per bucket of 32 dsts. Keys for a whole 64-group
//         come from ONE lane-strided load -> no vmcnt(0) drains in the gather
//         stream. Ordered-u16 ds_max; epilogue decodes + BN + coalesced write.
__global__ __launch_bounds__(256) void pool_fused_kernel(
    const int* __restrict__ gOffs, const int* __restrict__ aux,
    const int* __restrict__ keys,
    const unsigned short* __restrict__ yq, const float* __restrict__ node,
    const float* __restrict__ weight, const float* __restrict__ gamma,
    const float* __restrict__ beta, const float* __restrict__ rmean,
    const float* __restrict__ rvar,
    float* __restrict__ out, int n_nodes, int n_edges, int nbuck)
{
    __shared__ int acc[BW * OUT_DIM];   // 8 KB
    const int tid = threadIdx.x;
    const int lane = tid & 63, wid = tid >> 6;
    const int b = blockIdx.x;

    {   // init to sentinel 0
        int4* p = (int4*)acc;
        for (int i = tid; i < BW * OUT_DIM / 4; i += 256)
            p[i] = make_int4(SENT, SENT, SENT, SENT);
    }
    __syncthreads();

    const int i0 = b * NBLK;
    const int beg = gOffs[i0] + aux[i0 >> 10];
    int end;
    if (b == nbuck - 1) end = n_edges;
    else {
        const int i1 = (b + 1) * NBLK;
        end = gOffs[i1] + aux[i1 >> 10];
    }

    const int cnt = end - beg;
    const int slice = (cnt + 3) >> 2;          // per-wave contiguous slice
    const int w_beg = beg + wid * slice;
    const int w_end = min(w_beg + slice, end);

    int j = w_beg;
    // 64 keys per lane-strided load; gather stream has no interior loads
    for (; j + 64 <= w_end; j += 64) {
        const int kv = keys[j + lane];
#pragma unroll
        for (int u = 0; u < 64; ++u) {
            const int key = __builtin_amdgcn_readlane(kv, u);
            const int src = key >> BW_LOG;
            const int dlo = key & (BW - 1);
            const unsigned int v = yq[(size_t)src * OUT_DIM + lane];
            atomicMax(&acc[dlo * OUT_DIM + lane], (int)v);
        }
    }
    // tail: one guarded lane-strided load, dynamic-count readlane sweep
    const int r = w_end - j;
    if (r > 0) {
        int idx = j + lane; if (idx >= w_end) idx = w_end - 1;
        const int kv = keys[idx];
        for (int u = 0; u < r; ++u) {
            const int key = __builtin_amdgcn_readlane(kv, u);
            const int src = key >> BW_LOG;
            const int dlo = key & (BW - 1);
            const unsigned int v = yq[(size_t)src * OUT_DIM + lane];
            atomicMax(&acc[dlo * OUT_DIM + lane], (int)v);
        }
    }
    __syncthreads();

    const float a  = gamma[lane] * __frsqrt_rn(rvar[lane] + BN_EPS);
    const float bp = beta[lane] - rmean[lane] * a;
    const float w29 = weight[lane * XDIM + 29] * a;
    const float w30 = weight[lane * XDIM + 30] * a;
    const float w31 = weight[lane * XDIM + 31] * a;

    for (int d = wid; d < BW; d += 4) {
        const int dg = b * BW + d;
        if (dg >= n_nodes) break;
        const int k = acc[d * OUT_DIM + lane];
        float rr;
        if (k == SENT) {
            rr = 0.0f;
        } else {
            const unsigned short enc = (unsigned short)k;
            const unsigned short h = (enc & 0x8000) ? (unsigned short)(enc ^ 0x8000)
                                                    : (unsigned short)(~enc);
            const float v = __half2float(__ushort_as_half(h));
            const float nx = node[(size_t)dg * 3 + 0];
            const float ny = node[(size_t)dg * 3 + 1];
            const float nz = node[(size_t)dg * 3 + 2];
            rr = v + (bp - (w29 * nx + w30 * ny + w31 * nz));
        }
        out[(size_t)dg * OUT_DIM + lane] = rr;
    }
}

// ===========================================================================
// Fallback path (workspace too small): round-1 direct atomic kernels
// ===========================================================================
__global__ void init_kernel(int4* __restrict__ out, int total4) {
    int t = blockIdx.x * blockDim.x + threadIdx.x;
    if (t < total4) out[t] = make_int4(INT_MIN, INT_MIN, INT_MIN, INT_MIN);
}

__global__ __launch_bounds__(256) void edge_atomic_kernel(
    const int* __restrict__ edges,
    const float* __restrict__ features, const float* __restrict__ node,
    const float* __restrict__ weight, const float* __restrict__ gamma,
    const float* __restrict__ beta, const float* __restrict__ rmean,
    const float* __restrict__ rvar,
    int* __restrict__ out, int n_edges, int epw)
{
    const int lane = threadIdx.x & 63;
    const int wave = (blockIdx.x * blockDim.x + threadIdx.x) >> 6;
    int e0 = wave * epw, e1 = e0 + epw;
    if (e1 > n_edges) e1 = n_edges;

    float w[XDIM];
    const float4* wp = (const float4*)(weight + lane * XDIM);
#pragma unroll
    for (int q = 0; q < 8; ++q) {
        float4 v = wp[q];
        w[4*q+0] = v.x; w[4*q+1] = v.y; w[4*q+2] = v.z; w[4*q+3] = v.w;
    }
    const float a = gamma[lane] * __frsqrt_rn(rvar[lane] + BN_EPS);
    const float bprime = beta[lane] - rmean[lane] * a;

    for (int e = e0; e < e1; ++e) {
        const int dst = edges[2*e+0], src = edges[2*e+1];
        float x[XDIM];
#pragma unroll
        for (int i = 0; i < IN_DIM; ++i) x[i] = features[(size_t)src * IN_DIM + i];
#pragma unroll
        for (int j = 0; j < 3; ++j)
            x[IN_DIM+j] = node[(size_t)src*3+j] - node[(size_t)dst*3+j];
        float acc = 0.0f;
#pragma unroll
        for (int i = 0; i < XDIM; ++i) acc = fmaf(x[i], w[i], acc);
        float msg = fmaf(acc, a, bprime);
        int bb = __float_as_int(msg);
        int key = (bb < 0) ? (bb ^ 0x7FFFFFFF) : bb;
        atomicMax(out + (size_t)dst * OUT_DIM + lane, key);
    }
}

__global__ void decode_kernel(int* __restrict__ out, int total) {
    int t = blockIdx.x * blockDim.x + threadIdx.x;
    if (t >= total) return;
    int k = out[t];
    float r;
    if (k == INT_MIN) r = 0.0f;
    else { int b = (k < 0) ? (k ^ 0x7FFFFFFF) : k; r = __int_as_float(b); }
    ((float*)out)[t] = r;
}

// ===========================================================================
extern "C" void kernel_launch(void* const* d_in, const int* in_sizes, int n_in,
                              void* d_out, int out_size, void* d_ws, size_t ws_size,
                              hipStream_t stream) {
    const float* node     = (const float*)d_in[0];
    const float* features = (const float*)d_in[1];
    const int*   edges    = (const int*)d_in[2];
    const float* weight   = (const float*)d_in[3];
    const float* gamma    = (const float*)d_in[4];
    const float* beta     = (const float*)d_in[5];
    const float* rmean    = (const float*)d_in[6];
    const float* rvar     = (const float*)d_in[7];

    const int n_nodes = in_sizes[0] / 3;
    const int n_edges = in_sizes[2] / 2;

    const int nbuck = (n_nodes + BW - 1) >> BW_LOG;       // 3125
    const int n_scan = nbuck * NBLK;                      // 200k
    const int nb_scan = (n_scan + 1023) / 1024;           // 196
    const int chunk = (n_edges + NBLK - 1) / NBLK;        // 25000

    // workspace layout
    size_t off = 0;
    auto alloc = [&](size_t bytes) { size_t r = off; off = (off + bytes + 15) & ~(size_t)15; return r; };
    size_t o_yq   = alloc((size_t)n_nodes * OUT_DIM * sizeof(unsigned short));
    size_t o_hist = alloc((size_t)n_scan * sizeof(int));
    size_t o_offs = alloc((size_t)n_scan * sizeof(int));
    size_t o_aux  = alloc((size_t)nb_scan * sizeof(int));
    size_t o_keys = alloc((size_t)n_edges * sizeof(int));
    const size_t need = off;

    const int npw = (n_nodes + TBLK * 4 - 1) / (TBLK * 4);

    if (ws_size >= need && nbuck <= MAXBUCK && n_nodes <= MAXBUCK * BW) {
        char* base  = (char*)d_ws;
        unsigned short* yq = (unsigned short*)(base + o_yq);
        int* gHist  = (int*)(base + o_hist);
        int* gOffs  = (int*)(base + o_offs);
        int* aux    = (int*)(base + o_aux);
        int* keys   = (int*)(base + o_keys);

        fused_tc_kernel<<<NBLK + TBLK, 256, 0, stream>>>(
            features, node, weight, gamma, rvar, yq,
            edges, gHist, n_nodes, npw, n_edges, nbuck, chunk);
        scan_a_kernel<<<nb_scan, 256, 0, stream>>>(gHist, n_scan, gOffs, aux);
        scan_b_kernel<<<1, 256, 0, stream>>>(aux, nb_scan);
        partition_kernel<<<NBLK, 256, 0, stream>>>(edges, gOffs, aux, keys,
                                                   n_edges, nbuck, chunk);
        pool_fused_kernel<<<nbuck, 256, 0, stream>>>(
            gOffs, aux, keys, yq, node, weight, gamma, beta, rmean, rvar,
            (float*)d_out, n_nodes, n_edges, nbuck);
    } else {
        int* out_i = (int*)d_out;
        const int total4 = out_size / 4;
        init_kernel<<<(total4 + 255) / 256, 256, 0, stream>>>((int4*)out_i, total4);
        const int n_waves = 8192;
        const int epw = (n_edges + n_waves - 1) / n_waves;
        edge_atomic_kernel<<<n_waves / 4, 256, 0, stream>>>(
            edges, features, node, weight, gamma, beta, rmean, rvar,
            out_i, n_edges, epw);
        decode_kernel<<<(out_size + 255) / 256, 256, 0, stream>>>(out_i, out_size);
    }
}

// Round 6
// 193.286 us; speedup vs baseline: 1.3624x; 1.3624x over previous
//
#include <hip/hip_runtime.h>
#include <hip/hip_fp16.h>

#define IN_DIM 29
#define XDIM 32
#define OUT_DIM 64
#define BN_EPS 1e-5f

#define BW      32       // dsts per bucket (LDS tile: 32*64*4 = 8 KB)
#define BW_LOG  5
#define TBLK    2048     // transform blocks inside fused kernel
#define MAXBUCK 4096     // static LDS arrays; n_nodes <= 131072
#define SENT    0        // ordered-u16 sentinel: any real enc > 0

// ===========================================================================
// out[d][o] = max_{src in N(d)} y[src][o] + (beta - a*mean - a*(W[:,29:32].node_d))[o]
// y[n][o] = a[o] * (W[o,:] . [feat_n; node_n]),  a = gamma*rsqrt(var+eps)
// y stored as monotone ordered-u16 fp16 encoding; empty segment -> 0.
// ===========================================================================

// --- K1: fused per-node transform (blocks >= nblk) + bucket histogram ------
__global__ __launch_bounds__(256) void fused_tc_kernel(
    const float* __restrict__ features, const float* __restrict__ node,
    const float* __restrict__ weight, const float* __restrict__ gamma,
    const float* __restrict__ rvar, unsigned short* __restrict__ yq,
    const int* __restrict__ edges, int* __restrict__ gHist,
    int n_nodes, int npw, int n_edges, int nbuck, int chunk, int nblk)
{
    if ((int)blockIdx.x < nblk) {
        // ---- count role ----
        __shared__ int h[MAXBUCK];
        for (int i = threadIdx.x; i < nbuck; i += 256) h[i] = 0;
        __syncthreads();
        const int e0 = blockIdx.x * chunk;
        const int e1 = min(e0 + chunk, n_edges);
        for (int e = e0 + threadIdx.x; e < e1; e += 256)
            atomicAdd(&h[edges[2*e] >> BW_LOG], 1);
        __syncthreads();
        for (int i = threadIdx.x; i < nbuck; i += 256)
            gHist[i * nblk + blockIdx.x] = h[i];
    } else {
        // ---- transform role ----
        const int lane = threadIdx.x & 63;
        const int wave = (((int)blockIdx.x - nblk) * 256 + (int)threadIdx.x) >> 6;
        int n0 = wave * npw;
        int n1 = n0 + npw; if (n1 > n_nodes) n1 = n_nodes;

        float w[XDIM];
        const float4* wp = (const float4*)(weight + lane * XDIM);
#pragma unroll
        for (int q = 0; q < 8; ++q) {
            float4 v = wp[q];
            w[4*q+0] = v.x; w[4*q+1] = v.y; w[4*q+2] = v.z; w[4*q+3] = v.w;
        }
        const float a = gamma[lane] * __frsqrt_rn(rvar[lane] + BN_EPS);

        for (int n = n0; n < n1; ++n) {
            const float* f = features + (size_t)n * IN_DIM;
            float acc = 0.0f;
#pragma unroll
            for (int i = 0; i < IN_DIM; ++i) acc = fmaf(f[i], w[i], acc);
            const float* nd = node + (size_t)n * 3;
#pragma unroll
            for (int j = 0; j < 3; ++j) acc = fmaf(nd[j], w[IN_DIM + j], acc);
            unsigned short hh = __half_as_ushort(__float2half(acc * a));
            unsigned short enc = (hh & 0x8000) ? (unsigned short)(~hh)
                                               : (unsigned short)(hh | 0x8000);
            yq[(size_t)n * OUT_DIM + lane] = enc;
        }
    }
}

// --- K2: in-place block scan (1024/block) + per-block totals in aux --------
__global__ __launch_bounds__(256) void scan_a_kernel(
    int* __restrict__ data, int n, int* __restrict__ aux)
{
    const int t = threadIdx.x;
    const int base = blockIdx.x * 1024 + t * 4;
    int v[4];
#pragma unroll
    for (int k = 0; k < 4; ++k) v[k] = (base + k < n) ? data[base + k] : 0;
    int tsum = v[0] + v[1] + v[2] + v[3];

    const int lane = t & 63, wv = t >> 6;
    int x = tsum;
#pragma unroll
    for (int off = 1; off < 64; off <<= 1) {
        int y = __shfl_up(x, off);
        if (lane >= off) x += y;
    }
    __shared__ int wsum[4];
    if (lane == 63) wsum[wv] = x;
    __syncthreads();
    int wexcl = 0;
    for (int i = 0; i < wv; ++i) wexcl += wsum[i];
    int run = wexcl + x - tsum;
#pragma unroll
    for (int k = 0; k < 4; ++k) {
        if (base + k < n) data[base + k] = run;
        run += v[k];
    }
    if (t == 255) aux[blockIdx.x] = run;
}

// --- K3: single-block parallel exclusive scan of aux -----------------------
__global__ __launch_bounds__(256) void scan_b_kernel(int* __restrict__ aux, int nb) {
    const int t = threadIdx.x;
    const int lane = t & 63, wv = t >> 6;
    __shared__ int wsum[4];
    __shared__ int s_run;
    if (t == 0) s_run = 0;
    __syncthreads();
    for (int base = 0; base < nb; base += 256) {
        const int i = base + t;
        int v = (i < nb) ? aux[i] : 0;
        int x = v;
#pragma unroll
        for (int off = 1; off < 64; off <<= 1) {
            int y = __shfl_up(x, off);
            if (lane >= off) x += y;
        }
        if (lane == 63) wsum[wv] = x;
        __syncthreads();
        int wexcl = 0;
        for (int k = 0; k < wv; ++k) wexcl += wsum[k];
        const int run = s_run;
        if (i < nb) aux[i] = run + wexcl + x - v;
        __syncthreads();
        if (t == 255) s_run = run + wexcl + x;
        __syncthreads();
    }
}

// --- K4: multisplit partition -> per-bucket contiguous key runs ------------
__global__ __launch_bounds__(512) void partition_kernel(
    const int* __restrict__ edges, const int* __restrict__ gOffs,
    const int* __restrict__ aux,
    int* __restrict__ keys, int n_edges, int nbuck, int chunk, int nblk)
{
    __shared__ int cur[MAXBUCK];
    for (int i = threadIdx.x; i < nbuck; i += 512) {
        const int idx = i * nblk + blockIdx.x;
        cur[i] = gOffs[idx] + aux[idx >> 10];
    }
    __syncthreads();
    const int e0 = blockIdx.x * chunk;
    const int e1 = min(e0 + chunk, n_edges);
    for (int e = e0 + threadIdx.x; e < e1; e += 512) {
        const int dst = edges[2*e], src = edges[2*e+1];
        const int b = dst >> BW_LOG;
        const int pos = atomicAdd(&cur[b], 1);
        keys[pos] = (dst & (BW - 1)) | (src << BW_LOG);
    }
}

// --- K5: fused pool. One WG per bucket of 32 dsts. Double-buffered batches
//         of 8 gathers held in live VGPR arrays -> forced MLP. Tail groups
//         padded by clamping (max is idempotent). ---------------------------
__global__ __launch_bounds__(256) void pool_fused_kernel(
    const int* __restrict__ gOffs, const int* __restrict__ aux,
    const int* __restrict__ keys,
    const unsigned short* __restrict__ yq, const float* __restrict__ node,
    const float* __restrict__ weight, const float* __restrict__ gamma,
    const float* __restrict__ beta, const float* __restrict__ rmean,
    const float* __restrict__ rvar,
    float* __restrict__ out, int n_nodes, int n_edges, int nbuck, int nblk)
{
    __shared__ int acc[BW * OUT_DIM];   // 8 KB
    const int tid = threadIdx.x;
    const int lane = tid & 63, wid = tid >> 6;
    const int b = blockIdx.x;

    {   // init to sentinel 0
        int4* p = (int4*)acc;
        for (int i = tid; i < BW * OUT_DIM / 4; i += 256)
            p[i] = make_int4(SENT, SENT, SENT, SENT);
    }
    __syncthreads();

    const int i0 = b * nblk;
    const int beg = gOffs[i0] + aux[i0 >> 10];
    int end;
    if (b == nbuck - 1) end = n_edges;
    else {
        const int i1 = (b + 1) * nblk;
        end = gOffs[i1] + aux[i1 >> 10];
    }

    const int cnt = end - beg;
    const int slice = (cnt + 3) >> 2;          // per-wave contiguous slice
    const int w_beg = beg + wid * slice;
    const int w_end = min(w_beg + slice, end);

    if (w_beg < w_end) {
        const int last = w_end - 1;
        int j = w_beg;
        int kv = keys[min(j + lane, last)];    // 64 keys (clamped pad)
        while (j < w_end) {
            const int jn = j + 64;
            int kv_n = 0;
            if (jn < w_end) kv_n = keys[min(jn + lane, last)];  // prefetch next block
            const int m = w_end - j < 64 ? w_end - j : 64;      // valid keys
            const int ng = (m + 7) >> 3;                        // groups of 8

            unsigned int va[8]; int da[8];
#pragma unroll
            for (int u = 0; u < 8; ++u) {
                const int uu = (u < m) ? u : (m - 1);
                const int key = __builtin_amdgcn_readlane(kv, uu);
                da[u] = key & (BW - 1);
                va[u] = yq[(size_t)((unsigned)key >> BW_LOG) * OUT_DIM + lane];
            }
            for (int g = 0; g < ng; ++g) {
                unsigned int vb[8]; int db[8];
                const bool more = (g + 1 < ng);
                if (more) {
#pragma unroll
                    for (int u = 0; u < 8; ++u) {
                        int uu = (g + 1) * 8 + u; uu = (uu < m) ? uu : (m - 1);
                        const int key = __builtin_amdgcn_readlane(kv, uu);
                        db[u] = key & (BW - 1);
                        vb[u] = yq[(size_t)((unsigned)key >> BW_LOG) * OUT_DIM + lane];
                    }
                }
#pragma unroll
                for (int u = 0; u < 8; ++u)
                    atomicMax(&acc[da[u] * OUT_DIM + lane], (int)va[u]);
                if (more) {
#pragma unroll
                    for (int u = 0; u < 8; ++u) { va[u] = vb[u]; da[u] = db[u]; }
                }
            }
            j = jn; kv = kv_n;
        }
    }
    __syncthreads();

    const float a  = gamma[lane] * __frsqrt_rn(rvar[lane] + BN_EPS);
    const float bp = beta[lane] - rmean[lane] * a;
    const float w29 = weight[lane * XDIM + 29] * a;
    const float w30 = weight[lane * XDIM + 30] * a;
    const float w31 = weight[lane * XDIM + 31] * a;

    for (int d = wid; d < BW; d += 4) {
        const int dg = b * BW + d;
        if (dg >= n_nodes) break;
        const int k = acc[d * OUT_DIM + lane];
        float rr;
        if (k == SENT) {
            rr = 0.0f;
        } else {
            const unsigned short enc = (unsigned short)k;
            const unsigned short h = (enc & 0x8000) ? (unsigned short)(enc ^ 0x8000)
                                                    : (unsigned short)(~enc);
            const float v = __half2float(__ushort_as_half(h));
            const float nx = node[(size_t)dg * 3 + 0];
            const float ny = node[(size_t)dg * 3 + 1];
            const float nz = node[(size_t)dg * 3 + 2];
            rr = v + (bp - (w29 * nx + w30 * ny + w31 * nz));
        }
        out[(size_t)dg * OUT_DIM + lane] = rr;
    }
}

// ===========================================================================
// Fallback path (workspace too small): direct atomic kernels
// ===========================================================================
__global__ void init_kernel(int4* __restrict__ out, int total4) {
    int t = blockIdx.x * blockDim.x + threadIdx.x;
    if (t < total4) out[t] = make_int4(INT_MIN, INT_MIN, INT_MIN, INT_MIN);
}

__global__ __launch_bounds__(256) void edge_atomic_kernel(
    const int* __restrict__ edges,
    const float* __restrict__ features, const float* __restrict__ node,
    const float* __restrict__ weight, const float* __restrict__ gamma,
    const float* __restrict__ beta, const float* __restrict__ rmean,
    const float* __restrict__ rvar,
    int* __restrict__ out, int n_edges, int epw)
{
    const int lane = threadIdx.x & 63;
    const int wave = (blockIdx.x * blockDim.x + threadIdx.x) >> 6;
    int e0 = wave * epw, e1 = e0 + epw;
    if (e1 > n_edges) e1 = n_edges;

    float w[XDIM];
    const float4* wp = (const float4*)(weight + lane * XDIM);
#pragma unroll
    for (int q = 0; q < 8; ++q) {
        float4 v = wp[q];
        w[4*q+0] = v.x; w[4*q+1] = v.y; w[4*q+2] = v.z; w[4*q+3] = v.w;
    }
    const float a = gamma[lane] * __frsqrt_rn(rvar[lane] + BN_EPS);
    const float bprime = beta[lane] - rmean[lane] * a;

    for (int e = e0; e < e1; ++e) {
        const int dst = edges[2*e+0], src = edges[2*e+1];
        float x[XDIM];
#pragma unroll
        for (int i = 0; i < IN_DIM; ++i) x[i] = features[(size_t)src * IN_DIM + i];
#pragma unroll
        for (int j = 0; j < 3; ++j)
            x[IN_DIM+j] = node[(size_t)src*3+j] - node[(size_t)dst*3+j];
        float acc = 0.0f;
#pragma unroll
        for (int i = 0; i < XDIM; ++i) acc = fmaf(x[i], w[i], acc);
        float msg = fmaf(acc, a, bprime);
        int bb = __float_as_int(msg);
        int key = (bb < 0) ? (bb ^ 0x7FFFFFFF) : bb;
        atomicMax(out + (size_t)dst * OUT_DIM + lane, key);
    }
}

__global__ void decode_kernel(int* __restrict__ out, int total) {
    int t = blockIdx.x * blockDim.x + threadIdx.x;
    if (t >= total) return;
    int k = out[t];
    float r;
    if (k == INT_MIN) r = 0.0f;
    else { int b = (k < 0) ? (k ^ 0x7FFFFFFF) : k; r = __int_as_float(b); }
    ((float*)out)[t] = r;
}

// ===========================================================================
extern "C" void kernel_launch(void* const* d_in, const int* in_sizes, int n_in,
                              void* d_out, int out_size, void* d_ws, size_t ws_size,
                              hipStream_t stream) {
    const float* node     = (const float*)d_in[0];
    const float* features = (const float*)d_in[1];
    const int*   edges    = (const int*)d_in[2];
    const float* weight   = (const float*)d_in[3];
    const float* gamma    = (const float*)d_in[4];
    const float* beta     = (const float*)d_in[5];
    const float* rmean    = (const float*)d_in[6];
    const float* rvar     = (const float*)d_in[7];

    const int n_nodes = in_sizes[0] / 3;
    const int n_edges = in_sizes[2] / 2;

    const int nbuck = (n_nodes + BW - 1) >> BW_LOG;       // 3125

    // pick largest NBLK whose workspace fits (in-place scan: one hist buffer)
    int nblk = 0; size_t o_yq=0, o_hist=0, o_aux=0, o_keys=0; size_t need = 0;
    for (int cand = 128; cand >= 32; cand >>= 1) {
        const int n_scan = nbuck * cand;
        const int nb_scan = (n_scan + 1023) / 1024;
        size_t off = 0;
        auto alloc = [&](size_t bytes) { size_t r = off; off = (off + bytes + 15) & ~(size_t)15; return r; };
        o_yq   = alloc((size_t)n_nodes * OUT_DIM * sizeof(unsigned short));
        o_hist = alloc((size_t)n_scan * sizeof(int));
        o_aux  = alloc((size_t)nb_scan * sizeof(int));
        o_keys = alloc((size_t)n_edges * sizeof(int));
        need = off;
        if (need <= ws_size) { nblk = cand; break; }
    }

    if (nblk > 0 && nbuck <= MAXBUCK && n_nodes <= MAXBUCK * BW) {
        const int n_scan = nbuck * nblk;
        const int nb_scan = (n_scan + 1023) / 1024;
        const int chunk = (n_edges + nblk - 1) / nblk;
        const int npw = (n_nodes + TBLK * 4 - 1) / (TBLK * 4);

        char* base  = (char*)d_ws;
        unsigned short* yq = (unsigned short*)(base + o_yq);
        int* gHist  = (int*)(base + o_hist);   // becomes gOffs after scan_a
        int* aux    = (int*)(base + o_aux);
        int* keys   = (int*)(base + o_keys);

        fused_tc_kernel<<<nblk + TBLK, 256, 0, stream>>>(
            features, node, weight, gamma, rvar, yq,
            edges, gHist, n_nodes, npw, n_edges, nbuck, chunk, nblk);
        scan_a_kernel<<<nb_scan, 256, 0, stream>>>(gHist, n_scan, aux);
        scan_b_kernel<<<1, 256, 0, stream>>>(aux, nb_scan);
        partition_kernel<<<nblk, 512, 0, stream>>>(edges, gHist, aux, keys,
                                                   n_edges, nbuck, chunk, nblk);
        pool_fused_kernel<<<nbuck, 256, 0, stream>>>(
            gHist, aux, keys, yq, node, weight, gamma, beta, rmean, rvar,
            (float*)d_out, n_nodes, n_edges, nbuck, nblk);
    } else {
        int* out_i = (int*)d_out;
        const int total4 = out_size / 4;
        init_kernel<<<(total4 + 255) / 256, 256, 0, stream>>>((int4*)out_i, total4);
        const int n_waves = 8192;
        const int epw = (n_edges + n_waves - 1) / n_waves;
        edge_atomic_kernel<<<n_waves / 4, 256, 0, stream>>>(
            edges, features, node, weight, gamma, beta, rmean, rvar,
            out_i, n_edges, epw);
        decode_kernel<<<(out_size + 255) / 256, 256, 0, stream>>>(out_i, out_size);
    }
}